// Round 1
// baseline (1073.968 us; speedup 1.0000x reference)
//
#include <hip/hip_runtime.h>

// Problem constants
constexpr int Bz = 512;   // batch
constexpr int Tz = 256;   // seq len
constexpr int Hz = 256;   // hidden
constexpr int Pz = 14;    // predict dim
constexpr int GB = 32;    // batch groups
constexpr int GS = 8;     // hidden slices per group
constexpr int BT = 16;    // batch per group (512/32)
constexpr int KP = 264;   // LDS h row stride (shorts)
constexpr int XS = 260;   // x LDS row stride (floats)

typedef short s8v __attribute__((ext_vector_type(8)));
typedef float f4v __attribute__((ext_vector_type(4)));
typedef unsigned long long u64;

__device__ __forceinline__ short f2bf(float f) {
  unsigned u = __float_as_uint(f);
  u = (u + 0x7fffu + ((u >> 16) & 1u)) >> 16;   // RNE
  return (short)u;
}
__device__ __forceinline__ float bf2f(short s) {
  return __uint_as_float(((unsigned)(unsigned short)s) << 16);
}
__device__ __forceinline__ float sigm(float v) { return 1.0f / (1.0f + __expf(-v)); }
__device__ __forceinline__ float tanh_f(float v) { return 1.0f - 2.0f / (__expf(2.0f * v) + 1.0f); }

__device__ __forceinline__ u64 llc_load64(const u64* p) {
  return __hip_atomic_load(p, __ATOMIC_RELAXED, __HIP_MEMORY_SCOPE_AGENT);
}
__device__ __forceinline__ void llc_store64(u64* p, u64 v) {
  __hip_atomic_store(p, v, __ATOMIC_RELAXED, __HIP_MEMORY_SCOPE_AGENT);
}

// R10 = R9 with the flag handshake removed entirely. Every stored h element
// is self-describing: u32 = (bf16 << 16) | step_tag. Stored as u64 pairs
// (each u32 half single-copy atomic -> no torn tag/payload). Consumers poll
// the DATA until all tags match; producers fire-and-forget (no vmcnt(0)
// drain, no flag store, no end-of-step barrier). This collapses 3 serialized
// LLC legs per step (store-drain, flag hop+poll, data round trip) into 1
// (store one-way + poll discovery).
//
// Tags: h0[s] stored with tag s+1 at parity s&1; h1[s-1] stored with tag s
// at parity (s-1)&1. memset(0) == "h[-1] = 0, tag 0" (consumer at s=0
// expects tag 0). Tags <= 256 fit u16, no wrap.
//
// Overwrite safety (replaces R9's flag argument): producer q writes parity-p
// tag s+1 only after q's step-s poll passed => every peer published step-s-1
// data => each peer's publish store was ISSUED after its sync1, whose
// per-wave s_waitcnt vmcnt(0) (R5-proven) guarantees ALL of that block's
// stage loads (both layers) had returned. So no reader still needs the
// overwritten tag-(s-1) words -> no livelock; 2-deep parity suffices.
//
// LDS h staging is double-buffered (parity s&1) so the only intra-block
// barrier per step is sync1 (LDS-visibility before MFMA).
__global__ void __launch_bounds__(256, 1)
lstm2(const float* __restrict__ x,
      const float* __restrict__ w_ih0, const float* __restrict__ w_hh0,
      const float* __restrict__ b_ih0, const float* __restrict__ b_hh0,
      const float* __restrict__ w_ih1, const float* __restrict__ w_hh1,
      const float* __restrict__ b_ih1, const float* __restrict__ b_hh1,
      const float* __restrict__ w_lin, const float* __restrict__ b_lin,
      float* __restrict__ out,
      u64* __restrict__ h0g, u64* __restrict__ h1g)
{
  const int blk  = blockIdx.x;
  const int g    = blk >> 3;      // batch group (32)
  const int sl   = blk & 7;       // hidden slice (8)
  const int tid  = threadIdx.x;
  const int w    = tid >> 6;      // wave
  const int lane = tid & 63;
  const int q    = lane >> 4;
  const int l15  = lane & 15;     // batch within group
  const int gbase = g * BT;

  extern __shared__ char smem_raw[];
  short* h0s = (short*)smem_raw;            // [2][BT][KP] double-buffered h0 stage
  short* h1s = h0s + 2 * BT * KP;           // [2][BT][KP] double-buffered h1 stage
  float* xls = (float*)(h1s + 2 * BT * KP); // [BT][XS] x preload
  float* wls = xls + BT * XS;               // [Pz][256] w_lin permuted to kpos order

  // ---- one-time: weights -> register A-fragments (permuted k gather) ----
  // kpos = sl*32 + w*8 + q*2 + j  <->  k_true = sl*32 + w*4 + q + 16*j
  s8v Wf[3][2][8];   // [mat: hh0, ih1, hh1][mti][kt]
  {
    const float* wsrc[3] = {w_hh0, w_ih1, w_hh1};
    #pragma unroll
    for (int mat = 0; mat < 3; ++mat) {
      #pragma unroll
      for (int mti = 0; mti < 2; ++mti) {
        int rr = (w + mti * 4) * 16 + l15;          // rr = unit*4+gate
        int grow = (rr & 3) * Hz + sl * 32 + (rr >> 2);
        const float* p = wsrc[mat] + (size_t)grow * Hz;
        #pragma unroll
        for (int kt = 0; kt < 8; ++kt) {
          s8v f;
          #pragma unroll
          for (int j = 0; j < 8; ++j) {
            int ktrue = kt * 32 + q * 4 + (j >> 1) + 16 * (j & 1);
            f[j] = f2bf(p[ktrue]);
          }
          Wf[mat][mti][kt] = f;
        }
      }
    }
  }
  // per-lane epilogue constants: units uA = w*4+q, uB = 16+uA; gates r=0..3
  const int uA = w * 4 + q, uB = 16 + w * 4 + q;
  float wihA[4], wihB[4], b0A[4], b0B[4], b1A[4], b1B[4];
  #pragma unroll
  for (int r = 0; r < 4; ++r) {
    int ga_ = r * Hz + sl * 32 + uA;
    int gb_ = r * Hz + sl * 32 + uB;
    wihA[r] = w_ih0[ga_];              wihB[r] = w_ih0[gb_];
    b0A[r]  = b_ih0[ga_] + b_hh0[ga_]; b0B[r]  = b_ih0[gb_] + b_hh0[gb_];
    b1A[r]  = b_ih1[ga_] + b_hh1[ga_]; b1B[r]  = b_ih1[gb_] + b_hh1[gb_];
  }
  float c0A = 0.f, c0B = 0.f, c1A = 0.f, c1B = 0.f;   // cell states in VGPRs

  // ---- preload x (this group's 16 batches) and permuted w_lin (head) ----
  for (int i = tid; i < BT * (Tz / 4); i += 256) {
    int b = i >> 6, c4 = i & 63;
    f4v v = *(const f4v*)(x + (size_t)(gbase + b) * Tz + c4 * 4);
    *(f4v*)(xls + b * XS + c4 * 4) = v;
  }
  if (sl == 0) {
    for (int i = tid; i < Pz * Hz; i += 256) {
      int p = i >> 8, kpos = i & 255;
      int sl2 = kpos >> 5, w2 = (kpos >> 3) & 3, q2 = (kpos >> 1) & 3, jj = kpos & 1;
      wls[i] = w_lin[p * Hz + sl2 * 32 + w2 * 4 + q2 + 16 * jj];
    }
  }

  // ---- per-thread stage addresses (u64 index into tagged layout) and LDS dst ----
  // global tagged layout: u64 idx = slw*2048 + bglob*4 + qq; word = two u32
  //   lo32 = (bfA<<16)|tag (unit w*4+qq), hi32 = (bfB<<16)|tag (unit 16+w*4+qq)
  unsigned offk[4], ldsk[4];
  #pragma unroll
  for (int k = 0; k < 4; ++k) {
    int i = tid + k * 256;
    int c = i & 1, b = (i >> 1) & 15, slw = i >> 5;
    offk[k] = (unsigned)(slw * 2048 + (gbase + b) * 4 + 2 * c);
    ldsk[k] = (unsigned)(b * KP + slw * 8 + c * 4);
  }

  const u64 TM = 0x0000FFFF0000FFFFull;

  for (int s = 0; s <= Tz; ++s) {
    // ---- A: tagged poll-load: h0[s-1] (tag s) and h1[s-2] (tag s-1) ----
    const u64* p0 = h0g + (size_t)((s + 1) & 1) * 65536;
    const u64* p1 = h1g + (size_t)(s & 1) * 65536;
    const u64 e0r = (u64)(unsigned)s * 0x0000000100000001ull;
    const u64 e1r = (u64)(unsigned)(s > 0 ? s - 1 : 0) * 0x0000000100000001ull;
    u64 v0[8], v1[8];
    #pragma unroll
    for (int k = 0; k < 4; ++k) {
      v0[2 * k]     = llc_load64(p0 + offk[k]);
      v0[2 * k + 1] = llc_load64(p0 + offk[k] + 1);
      v1[2 * k]     = llc_load64(p1 + offk[k]);
      v1[2 * k + 1] = llc_load64(p1 + offk[k] + 1);
    }
    for (;;) {
      unsigned miss = 0;
      #pragma unroll
      for (int j = 0; j < 8; ++j) {
        if ((v0[j] & TM) != e0r) miss |= 1u << j;
        if ((v1[j] & TM) != e1r) miss |= 1u << (8 + j);
      }
      if (!miss) break;
      __builtin_amdgcn_s_sleep(1);
      #pragma unroll
      for (int j = 0; j < 8; ++j) {
        if (miss & (1u << j))       v0[j] = llc_load64(p0 + offk[j >> 1] + (j & 1));
        if (miss & (1u << (8 + j))) v1[j] = llc_load64(p1 + offk[j >> 1] + (j & 1));
      }
    }

    // ---- B: extract payloads -> LDS stage buffer (parity s&1) ----
    short* hb0 = h0s + (s & 1) * (BT * KP);
    short* hb1 = h1s + (s & 1) * (BT * KP);
    #pragma unroll
    for (int k = 0; k < 4; ++k) {
      unsigned a0 = (unsigned)((v0[2 * k] >> 16) & 0xFFFFu)     | ((unsigned)(v0[2 * k] >> 48) << 16);
      unsigned a1 = (unsigned)((v0[2 * k + 1] >> 16) & 0xFFFFu) | ((unsigned)(v0[2 * k + 1] >> 48) << 16);
      *(u64*)(hb0 + ldsk[k]) = (u64)a0 | ((u64)a1 << 32);
      unsigned b0 = (unsigned)((v1[2 * k] >> 16) & 0xFFFFu)     | ((unsigned)(v1[2 * k] >> 48) << 16);
      unsigned b1 = (unsigned)((v1[2 * k + 1] >> 16) & 0xFFFFu) | ((unsigned)(v1[2 * k + 1] >> 48) << 16);
      *(u64*)(hb1 + ldsk[k]) = (u64)b0 | ((u64)b1 << 32);
    }
    __syncthreads();   // sync1: staged LDS visible; per-wave vmcnt(0) also
                       // anchors the overwrite-safety chain (see header)

    // ---- C: fused MFMA (L0: 16, L1: 32); weights from regs; 16 b128 reads ----
    f4v a0A = {0.f,0.f,0.f,0.f}, a0B = {0.f,0.f,0.f,0.f};
    f4v a1A = {0.f,0.f,0.f,0.f}, a1B = {0.f,0.f,0.f,0.f};
    const short* H0f = hb0 + l15 * KP + q * 8;
    const short* H1f = hb1 + l15 * KP + q * 8;
    #pragma unroll
    for (int kt = 0; kt < 8; ++kt) {
      s8v h0v = *(const s8v*)(H0f + kt * 32);
      s8v h1v = *(const s8v*)(H1f + kt * 32);
      a0A = __builtin_amdgcn_mfma_f32_16x16x32_bf16(Wf[0][0][kt], h0v, a0A, 0, 0, 0);
      a0B = __builtin_amdgcn_mfma_f32_16x16x32_bf16(Wf[0][1][kt], h0v, a0B, 0, 0, 0);
      a1A = __builtin_amdgcn_mfma_f32_16x16x32_bf16(Wf[1][0][kt], h0v, a1A, 0, 0, 0);
      a1B = __builtin_amdgcn_mfma_f32_16x16x32_bf16(Wf[1][1][kt], h0v, a1B, 0, 0, 0);
      a1A = __builtin_amdgcn_mfma_f32_16x16x32_bf16(Wf[2][0][kt], h1v, a1A, 0, 0, 0);
      a1B = __builtin_amdgcn_mfma_f32_16x16x32_bf16(Wf[2][1][kt], h1v, a1B, 0, 0, 0);
    }

    // ---- D: in-register epilogues -> bf16 payloads ----
    unsigned hA0 = 0, hB0 = 0, hA1 = 0, hB1 = 0;
    if (s < Tz) {
      float xv = xls[l15 * XS + s];
      float iA = sigm  (a0A[0] + xv * wihA[0] + b0A[0]);
      float fA = sigm  (a0A[1] + xv * wihA[1] + b0A[1]);
      float gA = tanh_f(a0A[2] + xv * wihA[2] + b0A[2]);
      float oA = sigm  (a0A[3] + xv * wihA[3] + b0A[3]);
      c0A = fA * c0A + iA * gA;
      float iB = sigm  (a0B[0] + xv * wihB[0] + b0B[0]);
      float fB = sigm  (a0B[1] + xv * wihB[1] + b0B[1]);
      float gB = tanh_f(a0B[2] + xv * wihB[2] + b0B[2]);
      float oB = sigm  (a0B[3] + xv * wihB[3] + b0B[3]);
      c0B = fB * c0B + iB * gB;
      hA0 = (unsigned)(unsigned short)f2bf(oA * tanh_f(c0A));
      hB0 = (unsigned)(unsigned short)f2bf(oB * tanh_f(c0B));
    }
    if (s >= 1) {
      float iA = sigm  (a1A[0] + b1A[0]);
      float fA = sigm  (a1A[1] + b1A[1]);
      float gA = tanh_f(a1A[2] + b1A[2]);
      float oA = sigm  (a1A[3] + b1A[3]);
      c1A = fA * c1A + iA * gA;
      float iB = sigm  (a1B[0] + b1B[0]);
      float fB = sigm  (a1B[1] + b1B[1]);
      float gB = tanh_f(a1B[2] + b1B[2]);
      float oB = sigm  (a1B[3] + b1B[3]);
      c1B = fB * c1B + iB * gB;
      hA1 = (unsigned)(unsigned short)f2bf(oA * tanh_f(c1A));
      hB1 = (unsigned)(unsigned short)f2bf(oB * tanh_f(c1B));
    }

    // ---- E: fire-and-forget tagged stores (no drain, no flag) ----
    {
      size_t base = (size_t)(sl * 4 + w) * 2048 + (size_t)(gbase + l15) * 4 + q;
      if (s < Tz) {
        unsigned tg = (unsigned)(s + 1);
        u64 wd = (u64)((hA0 << 16) | tg) | ((u64)((hB0 << 16) | tg) << 32);
        llc_store64(h0g + (size_t)(s & 1) * 65536 + base, wd);
      }
      if (s >= 1) {
        unsigned tg = (unsigned)s;
        u64 wd = (u64)((hA1 << 16) | tg) | ((u64)((hB1 << 16) | tg) << 32);
        llc_store64(h1g + (size_t)((s - 1) & 1) * 65536 + base, wd);
      }
    }
    // no end-of-step barrier: LDS stage is double-buffered, readiness is in-band
  }

  // ---- final head (sl==0 blocks): out = h1[T-1] @ w_lin^T + b_lin ----
  if (sl == 0) {
    const u64* p1 = h1g + (size_t)((Tz - 1) & 1) * 65536;
    const u64 er = (u64)(unsigned)Tz * 0x0000000100000001ull;
    u64 v[8];
    #pragma unroll
    for (int k = 0; k < 4; ++k) {
      v[2 * k]     = llc_load64(p1 + offk[k]);
      v[2 * k + 1] = llc_load64(p1 + offk[k] + 1);
    }
    for (;;) {
      unsigned miss = 0;
      #pragma unroll
      for (int j = 0; j < 8; ++j)
        if ((v[j] & TM) != er) miss |= 1u << j;
      if (!miss) break;
      __builtin_amdgcn_s_sleep(1);
      #pragma unroll
      for (int j = 0; j < 8; ++j)
        if (miss & (1u << j)) v[j] = llc_load64(p1 + offk[j >> 1] + (j & 1));
    }
    // stage into h0s buffer 1 (last loop iter s=Tz used buffer 0; buffer 1's
    // readers all passed sync1(s=Tz) -> safe without an extra barrier)
    short* hb = h0s + 1 * (BT * KP);
    #pragma unroll
    for (int k = 0; k < 4; ++k) {
      unsigned a0 = (unsigned)((v[2 * k] >> 16) & 0xFFFFu)     | ((unsigned)(v[2 * k] >> 48) << 16);
      unsigned a1 = (unsigned)((v[2 * k + 1] >> 16) & 0xFFFFu) | ((unsigned)(v[2 * k + 1] >> 48) << 16);
      *(u64*)(hb + ldsk[k]) = (u64)a0 | ((u64)a1 << 32);
    }
    __syncthreads();
    for (int i = tid; i < BT * Pz; i += 256) {
      int b = i / Pz, p = i - b * Pz;
      const float* wr = wls + p * Hz;
      float acc = b_lin[p];
      for (int kk = 0; kk < Hz; ++kk)
        acc += bf2f(hb[b * KP + kk]) * wr[kk];   // both in kpos order
      out[(gbase + b) * Pz + p] = acc;
    }
  }
}

extern "C" void kernel_launch(void* const* d_in, const int* in_sizes, int n_in,
                              void* d_out, int out_size, void* d_ws, size_t ws_size,
                              hipStream_t stream) {
  const float* x     = (const float*)d_in[0];
  const float* w_ih0 = (const float*)d_in[1];
  const float* w_hh0 = (const float*)d_in[2];
  const float* b_ih0 = (const float*)d_in[3];
  const float* b_hh0 = (const float*)d_in[4];
  const float* w_ih1 = (const float*)d_in[5];
  const float* w_hh1 = (const float*)d_in[6];
  const float* b_ih1 = (const float*)d_in[7];
  const float* b_hh1 = (const float*)d_in[8];
  const float* w_lin = (const float*)d_in[9];
  const float* b_lin = (const float*)d_in[10];
  float* out = (float*)d_out;

  unsigned char* ws = (unsigned char*)d_ws;
  u64* h0g = (u64*)ws;                     // [2][65536] u64 tagged (512 KB/parity)
  u64* h1g = (u64*)(ws + (1 << 20));       // [2][65536] u64 tagged
  // memset(0): payload bf16 0x0000 == initial hidden state AND tag 0 ==
  // "h[-1] ready" -- no init kernel, no flags.
  hipMemsetAsync(d_ws, 0, 2 << 20, stream);

  size_t lds_bytes = (size_t)(4 * BT) * KP * 2     // h staging, double-buffered x2 layers
                   + (size_t)(BT * XS) * 4         // x preload
                   + (size_t)(Pz * Hz) * 4;        // permuted w_lin (head)
  hipFuncSetAttribute((const void*)lstm2,
                      hipFuncAttributeMaxDynamicSharedMemorySize, (int)lds_bytes);
  lstm2<<<GB * GS, 256, lds_bytes, stream>>>(x, w_ih0, w_hh0, b_ih0, b_hh0,
                                             w_ih1, w_hh1, b_ih1, b_hh1,
                                             w_lin, b_lin, out, h0g, h1g);
}